// Round 1
// baseline (600.217 us; speedup 1.0000x reference)
//
#include <hip/hip_runtime.h>
#include <math.h>

#define B_ 16
#define NH_ 256
#define NE_ 8192
#define ED_ 256
#define L_ 256
#define NCH 32                 // code chunks -> grid.x
#define CHUNK (NE_ / NCH)      // 256 codes per block
#define GROUPS (CHUNK / 32)    // 8 groups of 32 codes
#define STRIDE_P (B_ * NCH * L_)   // 131072 per field; 6 fields = 786432 < 1048576 (z_q region)
#define LOSS_IDX 1048576
#define IND_BASE 1048577
#define KLW 0.0005f

// ---------------- Kernel 1: fused GEMM + per-chunk reductions ----------------
// grid (NCH, B), block 256 (one thread per position p).
// Each block: 256 codes x 256 positions, K=256. Partials written into d_out's
// z_q region (overwritten later by k3).
__global__ __launch_bounds__(256) void k1_logits(
    const float* __restrict__ z, const float* __restrict__ pw,
    const float* __restrict__ pb, const float* __restrict__ gum,
    float* __restrict__ out)
{
    // A tile transposed: At[c][n], stride 40 floats (160B, 16B-aligned for b128 reads)
    __shared__ float At[256 * 40];
    const int tid = threadIdx.x;
    const int ch = blockIdx.x, b = blockIdx.y;
    const int n_c0 = ch * CHUNK;
    const float* zb = z + (size_t)b * NH_ * L_ + tid;   // X[c][p] = zb[c*256]

    float dmax = -INFINITY, smax = -INFINITY, S = 0.f, T = 0.f;
    int didx = 0, sidx = 0;

    for (int g = 0; g < GROUPS; ++g) {
        const int n0 = n_c0 + g * 32;
        __syncthreads();
        // stage A: At[c=tid][n] = pw[(n0+n)*256 + c]  (global reads coalesced per n)
        {
            const float* src = pw + (size_t)n0 * NH_ + tid;
            #pragma unroll
            for (int n = 0; n < 32; ++n)
                At[tid * 40 + n] = src[n * NH_];
        }
        __syncthreads();

        float acc[32];
        #pragma unroll
        for (int n = 0; n < 32; ++n) acc[n] = 0.f;

        for (int c = 0; c < 256; ++c) {
            float xc = zb[c * L_];                 // coalesced across lanes, L2-hot
            const float* ar = &At[c * 40];         // wave-uniform -> broadcast b128 reads
            #pragma unroll
            for (int j = 0; j < 8; ++j) {
                float4 a = *(const float4*)(ar + j * 4);
                acc[j * 4 + 0] = fmaf(a.x, xc, acc[j * 4 + 0]);
                acc[j * 4 + 1] = fmaf(a.y, xc, acc[j * 4 + 1]);
                acc[j * 4 + 2] = fmaf(a.z, xc, acc[j * 4 + 2]);
                acc[j * 4 + 3] = fmaf(a.w, xc, acc[j * 4 + 3]);
            }
        }

        // fold this 32-code group into running reductions (ascending n => argmax
        // keeps first occurrence via strict >, matching jnp.argmax)
        const float* gp = gum + ((size_t)b * NE_ + n0) * L_ + tid;
        #pragma unroll
        for (int n = 0; n < 32; ++n) {
            const int ng = n0 + n;
            float l = acc[n] + pb[ng];             // uniform scalar load
            if (l > dmax) { dmax = l; didx = ng; }
            float sv = l + gp[n * L_];             // coalesced gumbel read
            if (sv > smax) { smax = sv; sidx = ng; }
            float e = expf(l);                     // |l| small: no overflow, m=0 basis
            S += e;
            T = fmaf(l, e, T);
        }
    }

    const int base = (b * NCH + ch) * L_ + tid;
    out[0 * STRIDE_P + base] = dmax;
    out[1 * STRIDE_P + base] = __int_as_float(didx);
    out[2 * STRIDE_P + base] = smax;
    out[3 * STRIDE_P + base] = __int_as_float(sidx);
    out[4 * STRIDE_P + base] = S;
    out[5 * STRIDE_P + base] = T;
    if (ch == 0 && b == 0 && tid == 0) out[LOSS_IDX] = 0.f;   // zero for k2 atomics
}

// ---------------- Kernel 2: combine chunks + mask + select + KL --------------
// grid (B), block 256 (one thread per position).
__global__ __launch_bounds__(256) void k2_combine(
    const float* __restrict__ noise, float* __restrict__ out)
{
    const int p = threadIdx.x, b = blockIdx.x;
    float dmax = -INFINITY, smax = -INFINITY, S = 0.f, T = 0.f;
    int didx = 0, sidx = 0;
    for (int ch = 0; ch < NCH; ++ch) {          // ascending chunk = ascending code idx
        const int base = (b * NCH + ch) * L_ + p;
        float dm = out[0 * STRIDE_P + base];
        int   di = __float_as_int(out[1 * STRIDE_P + base]);
        float sm = out[2 * STRIDE_P + base];
        int   si = __float_as_int(out[3 * STRIDE_P + base]);
        S += out[4 * STRIDE_P + base];
        T += out[5 * STRIDE_P + base];
        if (dm > dmax) { dmax = dm; didx = di; }
        if (sm > smax) { smax = sm; sidx = si; }
    }

    // mask: rank of noise within row (stable argsort semantics)
    __shared__ float nz[256];
    nz[p] = noise[b * L_ + p];
    __syncthreads();
    const float myv = nz[p];
    int rank = 0;
    for (int j = 0; j < 256; ++j) {
        float v = nz[j];
        rank += (v < myv) || (v == myv && j < p);
    }
    const int sel = (rank >= 128) ? sidx : didx;   // mask=1 -> stochastic branch
    out[IND_BASE + b * L_ + p] = (float)sel;

    // KL to uniform: sum_n qy*log(qy*NE) = T/S - log S + log NE   (m=0 basis)
    float kl = T / S - logf(S) + logf((float)NE_);
    __shared__ float red[256];
    red[p] = kl;
    __syncthreads();
    for (int s = 128; s > 0; s >>= 1) {
        if (p < s) red[p] += red[p + s];
        __syncthreads();
    }
    if (p == 0) atomicAdd(&out[LOSS_IDX], (KLW / 4096.f) * red[0]);
}

// ---------------- Kernel 3: z_q gather from codebook -------------------------
// grid (8, B), block 256. Reads ind (already in d_out, outside z_q region),
// writes z_q coalesced; embed gathers hit L2 (8 MiB codebook).
__global__ __launch_bounds__(256) void k3_gather(
    const float* __restrict__ emb, float* __restrict__ out)
{
    const int p = threadIdx.x;
    const int ds = blockIdx.x, b = blockIdx.y;
    const int sel = (int)out[IND_BASE + b * L_ + p];
    const float* er = emb + (size_t)sel * ED_;
    #pragma unroll
    for (int i = 0; i < 32; ++i) {
        const int d = ds * 32 + i;
        out[((size_t)(b * ED_ + d)) * L_ + p] = er[d];
    }
}

extern "C" void kernel_launch(void* const* d_in, const int* in_sizes, int n_in,
                              void* d_out, int out_size, void* d_ws, size_t ws_size,
                              hipStream_t stream) {
    const float* z     = (const float*)d_in[0];
    const float* pw    = (const float*)d_in[1];
    const float* pb    = (const float*)d_in[2];
    const float* emb   = (const float*)d_in[3];
    const float* gum   = (const float*)d_in[4];
    const float* noise = (const float*)d_in[5];
    float* out = (float*)d_out;

    hipLaunchKernelGGL(k1_logits, dim3(NCH, B_), dim3(256), 0, stream, z, pw, pb, gum, out);
    hipLaunchKernelGGL(k2_combine, dim3(B_), dim3(256), 0, stream, noise, out);
    hipLaunchKernelGGL(k3_gather, dim3(8, B_), dim3(256), 0, stream, emb, out);
}